// Round 12
// baseline (818.972 us; speedup 1.0000x reference)
//
#include <hip/hip_runtime.h>
#include <hip/hip_bf16.h>
#include <hip/hip_fp16.h>

#define DE 128
#define NPB 16          // nodes per block in mlp kernel (8 groups x 2 nodes)
#define CAP 64          // bucket capacity per (relation,node); Poisson(10) tail @64 ~ 1e-30

typedef float f4 __attribute__((ext_vector_type(4)));

// ---------------------------------------------------------------------------
// One-pass bucket fill (R11, unchanged)
// ---------------------------------------------------------------------------
__global__ void fill_direct(const int* __restrict__ d0, const int* __restrict__ d1,
                            const int* __restrict__ d2, int* __restrict__ cnt,
                            int* __restrict__ eid, int N, int n0, int n1, int n2) {
    int i = blockIdx.x * blockDim.x + threadIdx.x;
    int total = n0 + n1 + n2;
    if (i >= total) return;
    int r, j;
    if (i < n0)            { r = 0; j = i; }
    else if (i < n0 + n1)  { r = 1; j = i - n0; }
    else                   { r = 2; j = i - n0 - n1; }
    const int* d = (r == 0) ? d0 : (r == 1) ? d1 : d2;
    int node = d[j];
    size_t slot = (size_t)r * N + node;
    int p = atomicAdd(&cnt[slot], 1);
    if (p < CAP) eid[(slot << 6) + p] = j;
}

// ---- Y store/load helpers (f32 or f16 workspace) ---------------------------
__device__ inline void storeY(float* Yw, size_t off, f4 v) {
    *reinterpret_cast<f4*>(Yw + off) = v;
}
__device__ inline void storeY(__half* Yw, size_t off, f4 v) {
    __half2 h0 = __floats2half2_rn(v[0], v[1]);
    __half2 h1 = __floats2half2_rn(v[2], v[3]);
    *reinterpret_cast<__half2*>(Yw + off)     = h0;
    *reinterpret_cast<__half2*>(Yw + off + 2) = h1;
}
__device__ inline f4 loadY(const float* Yw, size_t off) {
    return *reinterpret_cast<const f4*>(Yw + off);
}
__device__ inline f4 loadY(const __half* Yw, size_t off) {
    __half2 h0 = *reinterpret_cast<const __half2*>(Yw + off);
    __half2 h1 = *reinterpret_cast<const __half2*>(Yw + off + 2);
    float2 a = __half22float2(h0), b = __half22float2(h1);
    f4 v = { a.x, a.y, b.x, b.y };
    return v;
}

// ---------------------------------------------------------------------------
// Gather kernel: one 32-lane group per (node, relation) pair. Zero LDS ->
// 8 blocks/CU, 32 waves (vs 24 for the fused kernel). Writes mean row Y
// (512B coalesced per group) to ws, pair-major: Yw[(node*3+r)*128 + ...].
// ---------------------------------------------------------------------------
template <typename YT>
__global__ __launch_bounds__(256, 8) void gather_k(
        const float* __restrict__ E0, const float* __restrict__ E1,
        const float* __restrict__ E2,
        const int* __restrict__ eid,   // [3*N*CAP]
        const int* __restrict__ cnt,   // [3,N]
        YT* __restrict__ Yw, int N) {
    const int g = threadIdx.x >> 5;
    const int t = threadIdx.x & 31;
    long long p = (long long)blockIdx.x * 8 + g;   // pair index, node-major
    if (p >= 3LL * N) return;
    int node = (int)(p / 3);
    int r    = (int)(p - (long long)node * 3);

    size_t slot = (size_t)r * N + node;
    int deg = cnt[slot];
    const int* el = eid + (slot << 6);
    const float* E = (r == 0) ? E0 : (r == 1) ? E1 : E2;

    f4 acc = {0.f, 0.f, 0.f, 0.f};
    int k = 0;
    for (; k + 8 <= deg; k += 8) {
        int e0 = el[k + 0], e1 = el[k + 1], e2 = el[k + 2], e3 = el[k + 3];
        int e4 = el[k + 4], e5 = el[k + 5], e6 = el[k + 6], e7 = el[k + 7];
        f4 v0 = __builtin_nontemporal_load(reinterpret_cast<const f4*>(E + (size_t)e0 * DE + t * 4));
        f4 v1 = __builtin_nontemporal_load(reinterpret_cast<const f4*>(E + (size_t)e1 * DE + t * 4));
        f4 v2 = __builtin_nontemporal_load(reinterpret_cast<const f4*>(E + (size_t)e2 * DE + t * 4));
        f4 v3 = __builtin_nontemporal_load(reinterpret_cast<const f4*>(E + (size_t)e3 * DE + t * 4));
        f4 v4 = __builtin_nontemporal_load(reinterpret_cast<const f4*>(E + (size_t)e4 * DE + t * 4));
        f4 v5 = __builtin_nontemporal_load(reinterpret_cast<const f4*>(E + (size_t)e5 * DE + t * 4));
        f4 v6 = __builtin_nontemporal_load(reinterpret_cast<const f4*>(E + (size_t)e6 * DE + t * 4));
        f4 v7 = __builtin_nontemporal_load(reinterpret_cast<const f4*>(E + (size_t)e7 * DE + t * 4));
        acc += ((v0 + v1) + (v2 + v3)) + ((v4 + v5) + (v6 + v7));
    }
    if (k + 4 <= deg) {
        int e0 = el[k + 0], e1 = el[k + 1], e2 = el[k + 2], e3 = el[k + 3];
        f4 v0 = __builtin_nontemporal_load(reinterpret_cast<const f4*>(E + (size_t)e0 * DE + t * 4));
        f4 v1 = __builtin_nontemporal_load(reinterpret_cast<const f4*>(E + (size_t)e1 * DE + t * 4));
        f4 v2 = __builtin_nontemporal_load(reinterpret_cast<const f4*>(E + (size_t)e2 * DE + t * 4));
        f4 v3 = __builtin_nontemporal_load(reinterpret_cast<const f4*>(E + (size_t)e3 * DE + t * 4));
        acc += (v0 + v1) + (v2 + v3);
        k += 4;
    }
    for (; k < deg; ++k) {
        int e = el[k];
        f4 v = __builtin_nontemporal_load(reinterpret_cast<const f4*>(E + (size_t)e * DE + t * 4));
        acc += v;
    }

    acc *= 1.0f / fmaxf((float)deg, 1.0f);
    storeY(Yw, (size_t)p * DE + t * 4, acc);
}

// ---------------------------------------------------------------------------
// MLP kernel: R11's proven attention+projection body; stages Y from ws.
// 8 groups x 2 nodes; wave-local, no barriers. LDS 24KB.
// ---------------------------------------------------------------------------
template <typename YT>
__global__ __launch_bounds__(256, 6) void mlp_k(
        const YT* __restrict__ Yw,
        const float* __restrict__ W1, const float* __restrict__ W2,
        const float* __restrict__ W3,
        float* __restrict__ out, int N) {
    const int g = threadIdx.x >> 5;
    const int t = threadIdx.x & 31;
    const int ln0 = g * 2;
    const int ln1 = ln0 + 1;

    __shared__ float Ysh[NPB][3][DE];    // 24 KB

    // ---- stage Y for the group's two nodes (coalesced 512B rows)
    #pragma unroll
    for (int n2 = 0; n2 < 2; ++n2) {
        const int ln = ln0 + n2;
        int node = blockIdx.x * NPB + ln;
        if (node >= N) node = N - 1;
        #pragma unroll
        for (int r = 0; r < 3; ++r) {
            f4 v = loadY(Yw, ((size_t)node * 3 + r) * DE + t * 4);
            *reinterpret_cast<f4*>(&Ysh[ln][r][t * 4]) = v;
        }
    }

    // ---- z GEMM: 6 rows x 4 cols per thread; one f4 weight load -> 24 FMA
    f4 z0 = {0,0,0,0}, z1 = {0,0,0,0}, z2 = {0,0,0,0};
    f4 z3 = {0,0,0,0}, z4 = {0,0,0,0}, z5 = {0,0,0,0};
    {
        const float* w1p = W1 + t * 4;
        #pragma unroll 4
        for (int d = 0; d < DE; ++d) {
            f4 w = *reinterpret_cast<const f4*>(w1p + (size_t)d * DE);
            float a0 = Ysh[ln0][0][d], a1 = Ysh[ln0][1][d], a2 = Ysh[ln0][2][d];
            float b0 = Ysh[ln1][0][d], b1 = Ysh[ln1][1][d], b2 = Ysh[ln1][2][d];
            z0 += a0 * w; z1 += a1 * w; z2 += a2 * w;
            z3 += b0 * w; z4 += b1 * w; z5 += b2 * w;
        }
    }

    // ---- scores + 32-lane reduce
    f4 w2v = *reinterpret_cast<const f4*>(W2 + t * 4);
    float s0 = 0.f, s1 = 0.f, s2 = 0.f, s3 = 0.f, s4 = 0.f, s5 = 0.f;
    #pragma unroll
    for (int j = 0; j < 4; ++j) {
        s0 = fmaf(tanhf(z0[j]), w2v[j], s0);
        s1 = fmaf(tanhf(z1[j]), w2v[j], s1);
        s2 = fmaf(tanhf(z2[j]), w2v[j], s2);
        s3 = fmaf(tanhf(z3[j]), w2v[j], s3);
        s4 = fmaf(tanhf(z4[j]), w2v[j], s4);
        s5 = fmaf(tanhf(z5[j]), w2v[j], s5);
    }
    #pragma unroll
    for (int m = 16; m >= 1; m >>= 1) {
        s0 += __shfl_xor(s0, m); s1 += __shfl_xor(s1, m); s2 += __shfl_xor(s2, m);
        s3 += __shfl_xor(s3, m); s4 += __shfl_xor(s4, m); s5 += __shfl_xor(s5, m);
    }

    // ---- softmax per node; OY overwrites Ysh[ln][0]
    {
        float mx = fmaxf(s0, fmaxf(s1, s2));
        float x0 = __expf(s0 - mx), x1 = __expf(s1 - mx), x2 = __expf(s2 - mx);
        float inv = 1.0f / (x0 + x1 + x2);
        f4 y0 = *reinterpret_cast<const f4*>(&Ysh[ln0][0][t * 4]);
        f4 y1 = *reinterpret_cast<const f4*>(&Ysh[ln0][1][t * 4]);
        f4 y2 = *reinterpret_cast<const f4*>(&Ysh[ln0][2][t * 4]);
        f4 oy = (x0 * inv) * y0 + (x1 * inv) * y1 + (x2 * inv) * y2;
        *reinterpret_cast<f4*>(&Ysh[ln0][0][t * 4]) = oy;
    }
    {
        float mx = fmaxf(s3, fmaxf(s4, s5));
        float x0 = __expf(s3 - mx), x1 = __expf(s4 - mx), x2 = __expf(s5 - mx);
        float inv = 1.0f / (x0 + x1 + x2);
        f4 y0 = *reinterpret_cast<const f4*>(&Ysh[ln1][0][t * 4]);
        f4 y1 = *reinterpret_cast<const f4*>(&Ysh[ln1][1][t * 4]);
        f4 y2 = *reinterpret_cast<const f4*>(&Ysh[ln1][2][t * 4]);
        f4 oy = (x0 * inv) * y0 + (x1 * inv) * y1 + (x2 * inv) * y2;
        *reinterpret_cast<f4*>(&Ysh[ln1][0][t * 4]) = oy;
    }

    // ---- out = OY @ W3, both nodes per weight load
    f4 o0 = {0,0,0,0}, o1 = {0,0,0,0};
    {
        const float* w3p = W3 + t * 4;
        #pragma unroll 4
        for (int d = 0; d < DE; ++d) {
            f4 w = *reinterpret_cast<const f4*>(w3p + (size_t)d * DE);
            float a = Ysh[ln0][0][d];
            float b = Ysh[ln1][0][d];
            o0 += a * w;
            o1 += b * w;
        }
    }
    {
        int node0 = blockIdx.x * NPB + ln0;
        int node1 = node0 + 1;
        if (node0 < N)
            *reinterpret_cast<f4*>(out + (size_t)node0 * DE + t * 4) = o0;
        if (node1 < N)
            *reinterpret_cast<f4*>(out + (size_t)node1 * DE + t * 4) = o1;
    }
}

// ---------------------------------------------------------------------------
// launch
// ---------------------------------------------------------------------------
extern "C" void kernel_launch(void* const* d_in, const int* in_sizes, int n_in,
                              void* d_out, int out_size, void* d_ws, size_t ws_size,
                              hipStream_t stream) {
    const float* E_C = (const float*)d_in[0];
    const float* E_D = (const float*)d_in[1];
    const float* E_M = (const float*)d_in[2];
    const int* dst_C = (const int*)d_in[3];
    const int* dst_D = (const int*)d_in[4];
    const int* dst_M = (const int*)d_in[5];
    const float* W1 = (const float*)d_in[7];
    const float* W2 = (const float*)d_in[8];
    const float* W3 = (const float*)d_in[9];
    float* out = (float*)d_out;

    const int N = out_size / DE;                     // 100000
    const int nE[3] = { in_sizes[3], in_sizes[4], in_sizes[5] };
    const int NEtot = nE[0] + nE[1] + nE[2];

    // workspace: eid[3*N*CAP] ints | cnt[3N] ints (padded to 16B) | Yw
    int* eid = (int*)d_ws;
    int* cnt = eid + (size_t)3 * N * CAP;
    size_t cnt_elems = (((size_t)3 * N + 3) / 4) * 4;      // 16B-align what follows
    char* after = (char*)(cnt + cnt_elems);
    size_t used = (size_t)(after - (char*)d_ws);
    size_t y_elems = (size_t)3 * N * DE;

    (void)hipMemsetAsync(cnt, 0, 3 * (size_t)N * sizeof(int), stream);

    {
        int blocks = (NEtot + 255) / 256;
        fill_direct<<<blocks, 256, 0, stream>>>(dst_C, dst_D, dst_M, cnt, eid,
                                                N, nE[0], nE[1], nE[2]);
    }

    const long long npairs = 3LL * N;
    const int gblocks = (int)((npairs + 7) / 8);
    const int mblocks = (N + NPB - 1) / NPB;

    if (used + y_elems * sizeof(float) <= ws_size) {
        float* Yw = (float*)after;
        gather_k<float><<<gblocks, 256, 0, stream>>>(E_C, E_D, E_M, eid, cnt, Yw, N);
        mlp_k<float><<<mblocks, 256, 0, stream>>>(Yw, W1, W2, W3, out, N);
    } else {
        __half* Yw = (__half*)after;
        gather_k<__half><<<gblocks, 256, 0, stream>>>(E_C, E_D, E_M, eid, cnt, Yw, N);
        mlp_k<__half><<<mblocks, 256, 0, stream>>>(Yw, W1, W2, W3, out, N);
    }
}

// Round 13
// 745.328 us; speedup vs baseline: 1.0988x; 1.0988x over previous
//
#include <hip/hip_runtime.h>
#include <hip/hip_bf16.h>
#include <hip/hip_fp16.h>

#define DE 128
#define NPB 16          // nodes per block (8 groups x 2 nodes, gathered serially)
#define CAP 64          // bucket capacity per (relation,node); Poisson(10) tail @64 ~ 1e-30

typedef float f4 __attribute__((ext_vector_type(4)));

// ---------------------------------------------------------------------------
// One-pass bucket fill (R11, unchanged)
// ---------------------------------------------------------------------------
__global__ void fill_direct(const int* __restrict__ d0, const int* __restrict__ d1,
                            const int* __restrict__ d2, int* __restrict__ cnt,
                            int* __restrict__ eid, int N, int n0, int n1, int n2) {
    int i = blockIdx.x * blockDim.x + threadIdx.x;
    int total = n0 + n1 + n2;
    if (i >= total) return;
    int r, j;
    if (i < n0)            { r = 0; j = i; }
    else if (i < n0 + n1)  { r = 1; j = i - n0; }
    else                   { r = 2; j = i - n0 - n1; }
    const int* d = (r == 0) ? d0 : (r == 1) ? d1 : d2;
    int node = d[j];
    size_t slot = (size_t)r * N + node;
    int p = atomicAdd(&cnt[slot], 1);
    if (p < CAP) eid[(slot << 6) + p] = j;
}

// ---------------------------------------------------------------------------
// Fused: gather-mean + tanh-gate attention + projection.
// 256 threads = 8 groups x 32 lanes; each group owns TWO nodes.
// Ysh staged in f16 -> 12 KB LDS -> occupancy is wave-slot capped (8 blocks,
// 32 waves/CU) instead of LDS capped (R12 lesson: occupancy was the gather's
// limiter; the split kernel's Y round-trip cost more than the MLP overlap).
// Gather accumulates f32; only staging is f16 (10x absmax headroom).
// Wave-local groups: no barriers anywhere.
// ---------------------------------------------------------------------------
__global__ __launch_bounds__(256, 8) void node_fused(
        const float* __restrict__ E0, const float* __restrict__ E1,
        const float* __restrict__ E2,
        const int* __restrict__ eid,   // [3*N*CAP]
        const int* __restrict__ cnt,   // [3,N]
        const float* __restrict__ W1, const float* __restrict__ W2,
        const float* __restrict__ W3,
        float* __restrict__ out, int N) {
    const int g = threadIdx.x >> 5;      // group 0..7
    const int t = threadIdx.x & 31;      // lane in group
    const int ln0 = g * 2;
    const int ln1 = ln0 + 1;

    __shared__ __half Ysh[NPB][3][DE];   // 12 KB total

    const float* Es[3] = { E0, E1, E2 };

    // ---- gather + mean for the group's two nodes (loop NOT unrolled)
    #pragma unroll 1
    for (int n2 = 0; n2 < 2; ++n2) {
        const int ln = ln0 + n2;
        int node = blockIdx.x * NPB + ln;
        if (node >= N) node = N - 1;     // clamp; final stores are guarded

        #pragma unroll
        for (int r = 0; r < 3; ++r) {
            size_t slot = (size_t)r * N + node;
            int deg = cnt[slot];
            const int* el = eid + (slot << 6);
            const float* E = Es[r];
            f4 acc = {0.f, 0.f, 0.f, 0.f};

            int k = 0;
            for (; k + 8 <= deg; k += 8) {
                int e0 = el[k + 0], e1 = el[k + 1], e2 = el[k + 2], e3 = el[k + 3];
                int e4 = el[k + 4], e5 = el[k + 5], e6 = el[k + 6], e7 = el[k + 7];
                f4 v0 = __builtin_nontemporal_load(reinterpret_cast<const f4*>(E + (size_t)e0 * DE + t * 4));
                f4 v1 = __builtin_nontemporal_load(reinterpret_cast<const f4*>(E + (size_t)e1 * DE + t * 4));
                f4 v2 = __builtin_nontemporal_load(reinterpret_cast<const f4*>(E + (size_t)e2 * DE + t * 4));
                f4 v3 = __builtin_nontemporal_load(reinterpret_cast<const f4*>(E + (size_t)e3 * DE + t * 4));
                f4 v4 = __builtin_nontemporal_load(reinterpret_cast<const f4*>(E + (size_t)e4 * DE + t * 4));
                f4 v5 = __builtin_nontemporal_load(reinterpret_cast<const f4*>(E + (size_t)e5 * DE + t * 4));
                f4 v6 = __builtin_nontemporal_load(reinterpret_cast<const f4*>(E + (size_t)e6 * DE + t * 4));
                f4 v7 = __builtin_nontemporal_load(reinterpret_cast<const f4*>(E + (size_t)e7 * DE + t * 4));
                acc += ((v0 + v1) + (v2 + v3)) + ((v4 + v5) + (v6 + v7));
            }
            if (k + 4 <= deg) {
                int e0 = el[k + 0], e1 = el[k + 1], e2 = el[k + 2], e3 = el[k + 3];
                f4 v0 = __builtin_nontemporal_load(reinterpret_cast<const f4*>(E + (size_t)e0 * DE + t * 4));
                f4 v1 = __builtin_nontemporal_load(reinterpret_cast<const f4*>(E + (size_t)e1 * DE + t * 4));
                f4 v2 = __builtin_nontemporal_load(reinterpret_cast<const f4*>(E + (size_t)e2 * DE + t * 4));
                f4 v3 = __builtin_nontemporal_load(reinterpret_cast<const f4*>(E + (size_t)e3 * DE + t * 4));
                acc += (v0 + v1) + (v2 + v3);
                k += 4;
            }
            for (; k < deg; ++k) {
                int e = el[k];
                f4 v = __builtin_nontemporal_load(reinterpret_cast<const f4*>(E + (size_t)e * DE + t * 4));
                acc += v;
            }

            float inv = 1.0f / fmaxf((float)deg, 1.0f);
            acc *= inv;
            __half2 h0 = __floats2half2_rn(acc[0], acc[1]);
            __half2 h1 = __floats2half2_rn(acc[2], acc[3]);
            *reinterpret_cast<__half2*>(&Ysh[ln][r][t * 4])     = h0;
            *reinterpret_cast<__half2*>(&Ysh[ln][r][t * 4 + 2]) = h1;
        }
    }

    // ---- z GEMM: 6 rows x 4 cols per thread, d stepped by 2 (half2 reads)
    f4 z0 = {0,0,0,0}, z1 = {0,0,0,0}, z2 = {0,0,0,0};
    f4 z3 = {0,0,0,0}, z4 = {0,0,0,0}, z5 = {0,0,0,0};
    {
        const float* w1p = W1 + t * 4;
        #pragma unroll 2
        for (int d = 0; d < DE; d += 2) {
            f4 wA = *reinterpret_cast<const f4*>(w1p + (size_t)d * DE);
            f4 wB = *reinterpret_cast<const f4*>(w1p + (size_t)(d + 1) * DE);
            float2 a0 = __half22float2(*reinterpret_cast<const __half2*>(&Ysh[ln0][0][d]));
            float2 a1 = __half22float2(*reinterpret_cast<const __half2*>(&Ysh[ln0][1][d]));
            float2 a2 = __half22float2(*reinterpret_cast<const __half2*>(&Ysh[ln0][2][d]));
            float2 b0 = __half22float2(*reinterpret_cast<const __half2*>(&Ysh[ln1][0][d]));
            float2 b1 = __half22float2(*reinterpret_cast<const __half2*>(&Ysh[ln1][1][d]));
            float2 b2 = __half22float2(*reinterpret_cast<const __half2*>(&Ysh[ln1][2][d]));
            z0 += a0.x * wA + a0.y * wB;
            z1 += a1.x * wA + a1.y * wB;
            z2 += a2.x * wA + a2.y * wB;
            z3 += b0.x * wA + b0.y * wB;
            z4 += b1.x * wA + b1.y * wB;
            z5 += b2.x * wA + b2.y * wB;
        }
    }

    // ---- scores + 32-lane reduce
    f4 w2v = *reinterpret_cast<const f4*>(W2 + t * 4);
    float s0 = 0.f, s1 = 0.f, s2 = 0.f, s3 = 0.f, s4 = 0.f, s5 = 0.f;
    #pragma unroll
    for (int j = 0; j < 4; ++j) {
        s0 = fmaf(tanhf(z0[j]), w2v[j], s0);
        s1 = fmaf(tanhf(z1[j]), w2v[j], s1);
        s2 = fmaf(tanhf(z2[j]), w2v[j], s2);
        s3 = fmaf(tanhf(z3[j]), w2v[j], s3);
        s4 = fmaf(tanhf(z4[j]), w2v[j], s4);
        s5 = fmaf(tanhf(z5[j]), w2v[j], s5);
    }
    #pragma unroll
    for (int m = 16; m >= 1; m >>= 1) {
        s0 += __shfl_xor(s0, m); s1 += __shfl_xor(s1, m); s2 += __shfl_xor(s2, m);
        s3 += __shfl_xor(s3, m); s4 += __shfl_xor(s4, m); s5 += __shfl_xor(s5, m);
    }

    // ---- softmax per node; OY overwrites Ysh[ln][0] (cols 4t..4t+3)
    {
        float mx = fmaxf(s0, fmaxf(s1, s2));
        float x0 = __expf(s0 - mx), x1 = __expf(s1 - mx), x2 = __expf(s2 - mx);
        float inv = 1.0f / (x0 + x1 + x2);
        float2 y0 = __half22float2(*reinterpret_cast<const __half2*>(&Ysh[ln0][0][t * 4]));
        float2 y0b = __half22float2(*reinterpret_cast<const __half2*>(&Ysh[ln0][0][t * 4 + 2]));
        float2 y1 = __half22float2(*reinterpret_cast<const __half2*>(&Ysh[ln0][1][t * 4]));
        float2 y1b = __half22float2(*reinterpret_cast<const __half2*>(&Ysh[ln0][1][t * 4 + 2]));
        float2 y2 = __half22float2(*reinterpret_cast<const __half2*>(&Ysh[ln0][2][t * 4]));
        float2 y2b = __half22float2(*reinterpret_cast<const __half2*>(&Ysh[ln0][2][t * 4 + 2]));
        float c0 = x0 * inv, c1 = x1 * inv, c2 = x2 * inv;
        float o0 = c0 * y0.x + c1 * y1.x + c2 * y2.x;
        float o1 = c0 * y0.y + c1 * y1.y + c2 * y2.y;
        float o2 = c0 * y0b.x + c1 * y1b.x + c2 * y2b.x;
        float o3 = c0 * y0b.y + c1 * y1b.y + c2 * y2b.y;
        *reinterpret_cast<__half2*>(&Ysh[ln0][0][t * 4])     = __floats2half2_rn(o0, o1);
        *reinterpret_cast<__half2*>(&Ysh[ln0][0][t * 4 + 2]) = __floats2half2_rn(o2, o3);
    }
    {
        float mx = fmaxf(s3, fmaxf(s4, s5));
        float x0 = __expf(s3 - mx), x1 = __expf(s4 - mx), x2 = __expf(s5 - mx);
        float inv = 1.0f / (x0 + x1 + x2);
        float2 y0 = __half22float2(*reinterpret_cast<const __half2*>(&Ysh[ln1][0][t * 4]));
        float2 y0b = __half22float2(*reinterpret_cast<const __half2*>(&Ysh[ln1][0][t * 4 + 2]));
        float2 y1 = __half22float2(*reinterpret_cast<const __half2*>(&Ysh[ln1][1][t * 4]));
        float2 y1b = __half22float2(*reinterpret_cast<const __half2*>(&Ysh[ln1][1][t * 4 + 2]));
        float2 y2 = __half22float2(*reinterpret_cast<const __half2*>(&Ysh[ln1][2][t * 4]));
        float2 y2b = __half22float2(*reinterpret_cast<const __half2*>(&Ysh[ln1][2][t * 4 + 2]));
        float c0 = x0 * inv, c1 = x1 * inv, c2 = x2 * inv;
        float o0 = c0 * y0.x + c1 * y1.x + c2 * y2.x;
        float o1 = c0 * y0.y + c1 * y1.y + c2 * y2.y;
        float o2 = c0 * y0b.x + c1 * y1b.x + c2 * y2b.x;
        float o3 = c0 * y0b.y + c1 * y1b.y + c2 * y2b.y;
        *reinterpret_cast<__half2*>(&Ysh[ln1][0][t * 4])     = __floats2half2_rn(o0, o1);
        *reinterpret_cast<__half2*>(&Ysh[ln1][0][t * 4 + 2]) = __floats2half2_rn(o2, o3);
    }

    // ---- out = OY @ W3, both nodes per weight load (OY in Ysh[.][0], f16)
    f4 o0 = {0,0,0,0}, o1 = {0,0,0,0};
    {
        const float* w3p = W3 + t * 4;
        #pragma unroll 2
        for (int d = 0; d < DE; d += 2) {
            f4 wA = *reinterpret_cast<const f4*>(w3p + (size_t)d * DE);
            f4 wB = *reinterpret_cast<const f4*>(w3p + (size_t)(d + 1) * DE);
            float2 a = __half22float2(*reinterpret_cast<const __half2*>(&Ysh[ln0][0][d]));
            float2 b = __half22float2(*reinterpret_cast<const __half2*>(&Ysh[ln1][0][d]));
            o0 += a.x * wA + a.y * wB;
            o1 += b.x * wA + b.y * wB;
        }
    }
    {
        int node0 = blockIdx.x * NPB + ln0;
        int node1 = node0 + 1;
        if (node0 < N)
            *reinterpret_cast<f4*>(out + (size_t)node0 * DE + t * 4) = o0;
        if (node1 < N)
            *reinterpret_cast<f4*>(out + (size_t)node1 * DE + t * 4) = o1;
    }
}

// ---------------------------------------------------------------------------
// launch
// ---------------------------------------------------------------------------
extern "C" void kernel_launch(void* const* d_in, const int* in_sizes, int n_in,
                              void* d_out, int out_size, void* d_ws, size_t ws_size,
                              hipStream_t stream) {
    const float* E_C = (const float*)d_in[0];
    const float* E_D = (const float*)d_in[1];
    const float* E_M = (const float*)d_in[2];
    const int* dst_C = (const int*)d_in[3];
    const int* dst_D = (const int*)d_in[4];
    const int* dst_M = (const int*)d_in[5];
    const float* W1 = (const float*)d_in[7];
    const float* W2 = (const float*)d_in[8];
    const float* W3 = (const float*)d_in[9];
    float* out = (float*)d_out;

    const int N = out_size / DE;                     // 100000
    const int nE[3] = { in_sizes[3], in_sizes[4], in_sizes[5] };
    const int NEtot = nE[0] + nE[1] + nE[2];

    // workspace (ints): eid[3*N*CAP] (76.8 MB) | cnt[3N]
    int* eid = (int*)d_ws;
    int* cnt = eid + (size_t)3 * N * CAP;

    (void)hipMemsetAsync(cnt, 0, 3 * (size_t)N * sizeof(int), stream);

    {
        int blocks = (NEtot + 255) / 256;
        fill_direct<<<blocks, 256, 0, stream>>>(dst_C, dst_D, dst_M, cnt, eid,
                                                N, nE[0], nE[1], nE[2]);
    }

    int nblocks = (N + NPB - 1) / NPB;
    node_fused<<<nblocks, 256, 0, stream>>>(
        E_C, E_D, E_M, eid, cnt, W1, W2, W3, out, N);
}

// Round 14
// 734.759 us; speedup vs baseline: 1.1146x; 1.0144x over previous
//
#include <hip/hip_runtime.h>
#include <hip/hip_bf16.h>
#include <hip/hip_fp16.h>

#define DE 128
#define NPB 16          // nodes per block (8 groups x 2 nodes, gathered serially)
#define CAP 64          // bucket capacity per (relation,node); Poisson(10) tail @64 ~ 1e-30

typedef float f4 __attribute__((ext_vector_type(4)));
typedef int   i4 __attribute__((ext_vector_type(4)));

// ---------------------------------------------------------------------------
// One-pass bucket fill, 4 edges/thread, relation = blockIdx.y (R13 residual
// diagnosis: 1-edge/thread issue overhead dominated; atomics/writes are ~70us)
// ---------------------------------------------------------------------------
__global__ __launch_bounds__(256) void fill_direct4(
        const int* __restrict__ d0, const int* __restrict__ d1,
        const int* __restrict__ d2, int* __restrict__ cnt,
        int* __restrict__ eid, int N, int n0, int n1, int n2) {
    const int r = blockIdx.y;
    const int nr = (r == 0) ? n0 : (r == 1) ? n1 : n2;
    const int* d = (r == 0) ? d0 : (r == 1) ? d1 : d2;
    const int base = (r == 0) ? 0 : (r == 1) ? n0 : n0 + n1;
    int* cnt_r = cnt + (size_t)r * N;

    int i = (blockIdx.x * 256 + threadIdx.x) * 4;
    if (i >= nr) return;
    if (i + 4 <= nr) {
        i4 nd = *reinterpret_cast<const i4*>(d + i);
        #pragma unroll
        for (int u = 0; u < 4; ++u) {
            int node = nd[u];
            int p = atomicAdd(&cnt_r[node], 1);
            if (p < CAP) eid[(((size_t)r * N + node) << 6) + p] = i + u;
        }
    } else {
        for (int u = 0; i + u < nr; ++u) {
            int node = d[i + u];
            int p = atomicAdd(&cnt_r[node], 1);
            if (p < CAP) eid[(((size_t)r * N + node) << 6) + p] = i + u;
        }
    }
}

// ---------------------------------------------------------------------------
// Fused: gather-mean + tanh-gate attention + projection. (R13 body; only
// change: 8-eid batches loaded as two int4 -> 2 VMEM instead of 8.)
// 256 threads = 8 groups x 32 lanes; each group owns TWO nodes.
// f16 Ysh staging (12 KB LDS, 8 blocks/CU); wave-local groups, no barriers.
// ---------------------------------------------------------------------------
__global__ __launch_bounds__(256, 8) void node_fused(
        const float* __restrict__ E0, const float* __restrict__ E1,
        const float* __restrict__ E2,
        const int* __restrict__ eid,   // [3*N*CAP]
        const int* __restrict__ cnt,   // [3,N]
        const float* __restrict__ W1, const float* __restrict__ W2,
        const float* __restrict__ W3,
        float* __restrict__ out, int N) {
    const int g = threadIdx.x >> 5;      // group 0..7
    const int t = threadIdx.x & 31;      // lane in group
    const int ln0 = g * 2;
    const int ln1 = ln0 + 1;

    __shared__ __half Ysh[NPB][3][DE];   // 12 KB total

    const float* Es[3] = { E0, E1, E2 };

    // ---- gather + mean for the group's two nodes (loop NOT unrolled)
    #pragma unroll 1
    for (int n2 = 0; n2 < 2; ++n2) {
        const int ln = ln0 + n2;
        int node = blockIdx.x * NPB + ln;
        if (node >= N) node = N - 1;     // clamp; final stores are guarded

        #pragma unroll
        for (int r = 0; r < 3; ++r) {
            size_t slot = (size_t)r * N + node;
            int deg = cnt[slot];
            const int* el = eid + (slot << 6);   // 256B-aligned bucket
            const float* E = Es[r];
            f4 acc = {0.f, 0.f, 0.f, 0.f};

            int k = 0;
            for (; k + 8 <= deg; k += 8) {
                i4 ea = *reinterpret_cast<const i4*>(el + k);
                i4 eb = *reinterpret_cast<const i4*>(el + k + 4);
                f4 v0 = __builtin_nontemporal_load(reinterpret_cast<const f4*>(E + (size_t)ea[0] * DE + t * 4));
                f4 v1 = __builtin_nontemporal_load(reinterpret_cast<const f4*>(E + (size_t)ea[1] * DE + t * 4));
                f4 v2 = __builtin_nontemporal_load(reinterpret_cast<const f4*>(E + (size_t)ea[2] * DE + t * 4));
                f4 v3 = __builtin_nontemporal_load(reinterpret_cast<const f4*>(E + (size_t)ea[3] * DE + t * 4));
                f4 v4 = __builtin_nontemporal_load(reinterpret_cast<const f4*>(E + (size_t)eb[0] * DE + t * 4));
                f4 v5 = __builtin_nontemporal_load(reinterpret_cast<const f4*>(E + (size_t)eb[1] * DE + t * 4));
                f4 v6 = __builtin_nontemporal_load(reinterpret_cast<const f4*>(E + (size_t)eb[2] * DE + t * 4));
                f4 v7 = __builtin_nontemporal_load(reinterpret_cast<const f4*>(E + (size_t)eb[3] * DE + t * 4));
                acc += ((v0 + v1) + (v2 + v3)) + ((v4 + v5) + (v6 + v7));
            }
            if (k + 4 <= deg) {
                i4 ea = *reinterpret_cast<const i4*>(el + k);
                f4 v0 = __builtin_nontemporal_load(reinterpret_cast<const f4*>(E + (size_t)ea[0] * DE + t * 4));
                f4 v1 = __builtin_nontemporal_load(reinterpret_cast<const f4*>(E + (size_t)ea[1] * DE + t * 4));
                f4 v2 = __builtin_nontemporal_load(reinterpret_cast<const f4*>(E + (size_t)ea[2] * DE + t * 4));
                f4 v3 = __builtin_nontemporal_load(reinterpret_cast<const f4*>(E + (size_t)ea[3] * DE + t * 4));
                acc += (v0 + v1) + (v2 + v3);
                k += 4;
            }
            for (; k < deg; ++k) {
                int e = el[k];
                f4 v = __builtin_nontemporal_load(reinterpret_cast<const f4*>(E + (size_t)e * DE + t * 4));
                acc += v;
            }

            float inv = 1.0f / fmaxf((float)deg, 1.0f);
            acc *= inv;
            __half2 h0 = __floats2half2_rn(acc[0], acc[1]);
            __half2 h1 = __floats2half2_rn(acc[2], acc[3]);
            *reinterpret_cast<__half2*>(&Ysh[ln][r][t * 4])     = h0;
            *reinterpret_cast<__half2*>(&Ysh[ln][r][t * 4 + 2]) = h1;
        }
    }

    // ---- z GEMM: 6 rows x 4 cols per thread, d stepped by 2 (half2 reads)
    f4 z0 = {0,0,0,0}, z1 = {0,0,0,0}, z2 = {0,0,0,0};
    f4 z3 = {0,0,0,0}, z4 = {0,0,0,0}, z5 = {0,0,0,0};
    {
        const float* w1p = W1 + t * 4;
        #pragma unroll 2
        for (int d = 0; d < DE; d += 2) {
            f4 wA = *reinterpret_cast<const f4*>(w1p + (size_t)d * DE);
            f4 wB = *reinterpret_cast<const f4*>(w1p + (size_t)(d + 1) * DE);
            float2 a0 = __half22float2(*reinterpret_cast<const __half2*>(&Ysh[ln0][0][d]));
            float2 a1 = __half22float2(*reinterpret_cast<const __half2*>(&Ysh[ln0][1][d]));
            float2 a2 = __half22float2(*reinterpret_cast<const __half2*>(&Ysh[ln0][2][d]));
            float2 b0 = __half22float2(*reinterpret_cast<const __half2*>(&Ysh[ln1][0][d]));
            float2 b1 = __half22float2(*reinterpret_cast<const __half2*>(&Ysh[ln1][1][d]));
            float2 b2 = __half22float2(*reinterpret_cast<const __half2*>(&Ysh[ln1][2][d]));
            z0 += a0.x * wA + a0.y * wB;
            z1 += a1.x * wA + a1.y * wB;
            z2 += a2.x * wA + a2.y * wB;
            z3 += b0.x * wA + b0.y * wB;
            z4 += b1.x * wA + b1.y * wB;
            z5 += b2.x * wA + b2.y * wB;
        }
    }

    // ---- scores + 32-lane reduce
    f4 w2v = *reinterpret_cast<const f4*>(W2 + t * 4);
    float s0 = 0.f, s1 = 0.f, s2 = 0.f, s3 = 0.f, s4 = 0.f, s5 = 0.f;
    #pragma unroll
    for (int j = 0; j < 4; ++j) {
        s0 = fmaf(tanhf(z0[j]), w2v[j], s0);
        s1 = fmaf(tanhf(z1[j]), w2v[j], s1);
        s2 = fmaf(tanhf(z2[j]), w2v[j], s2);
        s3 = fmaf(tanhf(z3[j]), w2v[j], s3);
        s4 = fmaf(tanhf(z4[j]), w2v[j], s4);
        s5 = fmaf(tanhf(z5[j]), w2v[j], s5);
    }
    #pragma unroll
    for (int m = 16; m >= 1; m >>= 1) {
        s0 += __shfl_xor(s0, m); s1 += __shfl_xor(s1, m); s2 += __shfl_xor(s2, m);
        s3 += __shfl_xor(s3, m); s4 += __shfl_xor(s4, m); s5 += __shfl_xor(s5, m);
    }

    // ---- softmax per node; OY overwrites Ysh[ln][0] (cols 4t..4t+3)
    {
        float mx = fmaxf(s0, fmaxf(s1, s2));
        float x0 = __expf(s0 - mx), x1 = __expf(s1 - mx), x2 = __expf(s2 - mx);
        float inv = 1.0f / (x0 + x1 + x2);
        float2 y0 = __half22float2(*reinterpret_cast<const __half2*>(&Ysh[ln0][0][t * 4]));
        float2 y0b = __half22float2(*reinterpret_cast<const __half2*>(&Ysh[ln0][0][t * 4 + 2]));
        float2 y1 = __half22float2(*reinterpret_cast<const __half2*>(&Ysh[ln0][1][t * 4]));
        float2 y1b = __half22float2(*reinterpret_cast<const __half2*>(&Ysh[ln0][1][t * 4 + 2]));
        float2 y2 = __half22float2(*reinterpret_cast<const __half2*>(&Ysh[ln0][2][t * 4]));
        float2 y2b = __half22float2(*reinterpret_cast<const __half2*>(&Ysh[ln0][2][t * 4 + 2]));
        float c0 = x0 * inv, c1 = x1 * inv, c2 = x2 * inv;
        float o0 = c0 * y0.x + c1 * y1.x + c2 * y2.x;
        float o1 = c0 * y0.y + c1 * y1.y + c2 * y2.y;
        float o2 = c0 * y0b.x + c1 * y1b.x + c2 * y2b.x;
        float o3 = c0 * y0b.y + c1 * y1b.y + c2 * y2b.y;
        *reinterpret_cast<__half2*>(&Ysh[ln0][0][t * 4])     = __floats2half2_rn(o0, o1);
        *reinterpret_cast<__half2*>(&Ysh[ln0][0][t * 4 + 2]) = __floats2half2_rn(o2, o3);
    }
    {
        float mx = fmaxf(s3, fmaxf(s4, s5));
        float x0 = __expf(s3 - mx), x1 = __expf(s4 - mx), x2 = __expf(s5 - mx);
        float inv = 1.0f / (x0 + x1 + x2);
        float2 y0 = __half22float2(*reinterpret_cast<const __half2*>(&Ysh[ln1][0][t * 4]));
        float2 y0b = __half22float2(*reinterpret_cast<const __half2*>(&Ysh[ln1][0][t * 4 + 2]));
        float2 y1 = __half22float2(*reinterpret_cast<const __half2*>(&Ysh[ln1][1][t * 4]));
        float2 y1b = __half22float2(*reinterpret_cast<const __half2*>(&Ysh[ln1][1][t * 4 + 2]));
        float2 y2 = __half22float2(*reinterpret_cast<const __half2*>(&Ysh[ln1][2][t * 4]));
        float2 y2b = __half22float2(*reinterpret_cast<const __half2*>(&Ysh[ln1][2][t * 4 + 2]));
        float c0 = x0 * inv, c1 = x1 * inv, c2 = x2 * inv;
        float o0 = c0 * y0.x + c1 * y1.x + c2 * y2.x;
        float o1 = c0 * y0.y + c1 * y1.y + c2 * y2.y;
        float o2 = c0 * y0b.x + c1 * y1b.x + c2 * y2b.x;
        float o3 = c0 * y0b.y + c1 * y1b.y + c2 * y2b.y;
        *reinterpret_cast<__half2*>(&Ysh[ln1][0][t * 4])     = __floats2half2_rn(o0, o1);
        *reinterpret_cast<__half2*>(&Ysh[ln1][0][t * 4 + 2]) = __floats2half2_rn(o2, o3);
    }

    // ---- out = OY @ W3, both nodes per weight load (OY in Ysh[.][0], f16)
    f4 o0 = {0,0,0,0}, o1 = {0,0,0,0};
    {
        const float* w3p = W3 + t * 4;
        #pragma unroll 2
        for (int d = 0; d < DE; d += 2) {
            f4 wA = *reinterpret_cast<const f4*>(w3p + (size_t)d * DE);
            f4 wB = *reinterpret_cast<const f4*>(w3p + (size_t)(d + 1) * DE);
            float2 a = __half22float2(*reinterpret_cast<const __half2*>(&Ysh[ln0][0][d]));
            float2 b = __half22float2(*reinterpret_cast<const __half2*>(&Ysh[ln1][0][d]));
            o0 += a.x * wA + a.y * wB;
            o1 += b.x * wA + b.y * wB;
        }
    }
    {
        int node0 = blockIdx.x * NPB + ln0;
        int node1 = node0 + 1;
        if (node0 < N)
            *reinterpret_cast<f4*>(out + (size_t)node0 * DE + t * 4) = o0;
        if (node1 < N)
            *reinterpret_cast<f4*>(out + (size_t)node1 * DE + t * 4) = o1;
    }
}

// ---------------------------------------------------------------------------
// launch
// ---------------------------------------------------------------------------
extern "C" void kernel_launch(void* const* d_in, const int* in_sizes, int n_in,
                              void* d_out, int out_size, void* d_ws, size_t ws_size,
                              hipStream_t stream) {
    const float* E_C = (const float*)d_in[0];
    const float* E_D = (const float*)d_in[1];
    const float* E_M = (const float*)d_in[2];
    const int* dst_C = (const int*)d_in[3];
    const int* dst_D = (const int*)d_in[4];
    const int* dst_M = (const int*)d_in[5];
    const float* W1 = (const float*)d_in[7];
    const float* W2 = (const float*)d_in[8];
    const float* W3 = (const float*)d_in[9];
    float* out = (float*)d_out;

    const int N = out_size / DE;                     // 100000
    const int nE[3] = { in_sizes[3], in_sizes[4], in_sizes[5] };
    const int nEmax = max(nE[0], max(nE[1], nE[2]));

    // workspace (ints): eid[3*N*CAP] (76.8 MB) | cnt[3N]
    int* eid = (int*)d_ws;
    int* cnt = eid + (size_t)3 * N * CAP;

    (void)hipMemsetAsync(cnt, 0, 3 * (size_t)N * sizeof(int), stream);

    {
        dim3 grid((nEmax + 1023) / 1024, 3);
        fill_direct4<<<grid, 256, 0, stream>>>(dst_C, dst_D, dst_M, cnt, eid,
                                               N, nE[0], nE[1], nE[2]);
    }

    int nblocks = (N + NPB - 1) / NPB;
    node_fused<<<nblocks, 256, 0, stream>>>(
        E_C, E_D, E_M, eid, cnt, W1, W2, W3, out, N);
}

// Round 15
// 593.845 us; speedup vs baseline: 1.3791x; 1.2373x over previous
//
#include <hip/hip_runtime.h>
#include <hip/hip_bf16.h>
#include <hip/hip_fp16.h>

#define DE 128
#define NPB 16          // nodes per block
#define CAP 64          // bucket capacity per (relation,node); Poisson(10) tail @64 ~ 1e-30

typedef float    f4 __attribute__((ext_vector_type(4)));
typedef int      i4 __attribute__((ext_vector_type(4)));
typedef _Float16 h8 __attribute__((ext_vector_type(8)));

// swizzled f16 index within a [rows][128] f16 LDS tile (XOR bank swizzle, G4)
__device__ __forceinline__ int swz(int row, int col) {
    return row * DE + (col ^ ((row & 7) << 3));
}

// ---------------------------------------------------------------------------
// One-pass bucket fill, 4 edges/thread, relation = blockIdx.y (R14)
// ---------------------------------------------------------------------------
__global__ __launch_bounds__(256) void fill_direct4(
        const int* __restrict__ d0, const int* __restrict__ d1,
        const int* __restrict__ d2, int* __restrict__ cnt,
        int* __restrict__ eid, int N, int n0, int n1, int n2) {
    const int r = blockIdx.y;
    const int nr = (r == 0) ? n0 : (r == 1) ? n1 : n2;
    const int* d = (r == 0) ? d0 : (r == 1) ? d1 : d2;
    int* cnt_r = cnt + (size_t)r * N;

    int i = (blockIdx.x * 256 + threadIdx.x) * 4;
    if (i >= nr) return;
    if (i + 4 <= nr) {
        i4 nd = *reinterpret_cast<const i4*>(d + i);
        #pragma unroll
        for (int u = 0; u < 4; ++u) {
            int node = nd[u];
            int p = atomicAdd(&cnt_r[node], 1);
            if (p < CAP) eid[(((size_t)r * N + node) << 6) + p] = i + u;
        }
    } else {
        for (int u = 0; i + u < nr; ++u) {
            int node = d[i + u];
            int p = atomicAdd(&cnt_r[node], 1);
            if (p < CAP) eid[(((size_t)r * N + node) << 6) + p] = i + u;
        }
    }
}

// ---------------------------------------------------------------------------
// Weight prep: W1T/W3T = f16 transpose ([n][k] layout so MFMA B-frags are
// contiguous in k). 16384 elements each.
// ---------------------------------------------------------------------------
__global__ void prep_w(const float* __restrict__ W1, const float* __restrict__ W3,
                       __half* __restrict__ W1T, __half* __restrict__ W3T) {
    int i = blockIdx.x * 256 + threadIdx.x;
    if (i < DE * DE) {
        int n = i >> 7, k = i & 127;
        W1T[i] = __float2half(W1[(size_t)k * DE + n]);
        W3T[i] = __float2half(W3[(size_t)k * DE + n]);
    }
}

// ---------------------------------------------------------------------------
// Fused: gather-mean (f32 acc -> f16 LDS) + MFMA attention MLP + MFMA proj.
// 256 threads = 4 waves. Phase 1: 8x32-lane groups gather 2 nodes each into
// Ysh[48][128] f16 (row = r*16 + local_node, XOR-swizzled). Phase 2: Z=Y@W1
// via mfma_f32_16x16x32_f16, wave w owns cols [32w,32w+32); tanh+W2 score,
// 16-lane shfl reduce, partials to LDS. Phase 3: per-node softmax + OY
// (overwrites Ysh rows 0..15). Phase 4: OUT = OY@W3T, guarded stores.
// D-layout (m89-verified): col = lane&15, row = (lane>>4)*4 + reg.
// A/B frags: elem j of lane l -> (m or n) = l&15, k = (l>>4)*8 + j.
// ---------------------------------------------------------------------------
__global__ __launch_bounds__(256, 6) void node_fused(
        const float* __restrict__ E0, const float* __restrict__ E1,
        const float* __restrict__ E2,
        const int* __restrict__ eid,   // [3*N*CAP]
        const int* __restrict__ cnt,   // [3,N]
        const __half* __restrict__ W1T,  // [128][128] f16, [n][k]
        const float* __restrict__ W2,    // [128] f32
        const __half* __restrict__ W3T,  // [128][128] f16, [n][k]
        float* __restrict__ out, int N) {
    const int tid = threadIdx.x;

    __shared__ __half Ysh[48 * DE];      // 12 KB, swizzled rows
    __shared__ float e_part[4][48];      // per-wave score partials

    const float* Es[3] = { E0, E1, E2 };

    // ================= phase 1: gather + mean =================
    {
        const int g = tid >> 5;          // group 0..7
        const int t = tid & 31;          // lane in group
        #pragma unroll 1
        for (int n2 = 0; n2 < 2; ++n2) {
            const int ln = g * 2 + n2;
            int node = blockIdx.x * NPB + ln;
            if (node >= N) node = N - 1;     // clamp; stores guarded later

            #pragma unroll
            for (int r = 0; r < 3; ++r) {
                size_t slot = (size_t)r * N + node;
                int deg = cnt[slot];
                const int* el = eid + (slot << 6);
                const float* E = Es[r];
                f4 acc = {0.f, 0.f, 0.f, 0.f};

                int k = 0;
                for (; k + 8 <= deg; k += 8) {
                    i4 ea = *reinterpret_cast<const i4*>(el + k);
                    i4 eb = *reinterpret_cast<const i4*>(el + k + 4);
                    f4 v0 = __builtin_nontemporal_load(reinterpret_cast<const f4*>(E + (size_t)ea[0] * DE + t * 4));
                    f4 v1 = __builtin_nontemporal_load(reinterpret_cast<const f4*>(E + (size_t)ea[1] * DE + t * 4));
                    f4 v2 = __builtin_nontemporal_load(reinterpret_cast<const f4*>(E + (size_t)ea[2] * DE + t * 4));
                    f4 v3 = __builtin_nontemporal_load(reinterpret_cast<const f4*>(E + (size_t)ea[3] * DE + t * 4));
                    f4 v4 = __builtin_nontemporal_load(reinterpret_cast<const f4*>(E + (size_t)eb[0] * DE + t * 4));
                    f4 v5 = __builtin_nontemporal_load(reinterpret_cast<const f4*>(E + (size_t)eb[1] * DE + t * 4));
                    f4 v6 = __builtin_nontemporal_load(reinterpret_cast<const f4*>(E + (size_t)eb[2] * DE + t * 4));
                    f4 v7 = __builtin_nontemporal_load(reinterpret_cast<const f4*>(E + (size_t)eb[3] * DE + t * 4));
                    acc += ((v0 + v1) + (v2 + v3)) + ((v4 + v5) + (v6 + v7));
                }
                if (k + 4 <= deg) {
                    i4 ea = *reinterpret_cast<const i4*>(el + k);
                    f4 v0 = __builtin_nontemporal_load(reinterpret_cast<const f4*>(E + (size_t)ea[0] * DE + t * 4));
                    f4 v1 = __builtin_nontemporal_load(reinterpret_cast<const f4*>(E + (size_t)ea[1] * DE + t * 4));
                    f4 v2 = __builtin_nontemporal_load(reinterpret_cast<const f4*>(E + (size_t)ea[2] * DE + t * 4));
                    f4 v3 = __builtin_nontemporal_load(reinterpret_cast<const f4*>(E + (size_t)ea[3] * DE + t * 4));
                    acc += (v0 + v1) + (v2 + v3);
                    k += 4;
                }
                for (; k < deg; ++k) {
                    int e = el[k];
                    f4 v = __builtin_nontemporal_load(reinterpret_cast<const f4*>(E + (size_t)e * DE + t * 4));
                    acc += v;
                }

                acc *= 1.0f / fmaxf((float)deg, 1.0f);
                int row = r * 16 + ln;
                int idx = swz(row, t * 4);
                *reinterpret_cast<__half2*>(&Ysh[idx])     = __floats2half2_rn(acc[0], acc[1]);
                *reinterpret_cast<__half2*>(&Ysh[idx + 2]) = __floats2half2_rn(acc[2], acc[3]);
            }
        }
    }
    __syncthreads();

    // ================= phase 2: Z = Y @ W1 (MFMA) + scores =================
    const int l  = tid & 63;             // lane in wave
    const int w  = tid >> 6;             // wave 0..3 -> cols [32w, 32w+32)
    const int lo = l & 15;
    const int hi = l >> 4;

    f4 z00 = {0,0,0,0}, z01 = {0,0,0,0};
    f4 z10 = {0,0,0,0}, z11 = {0,0,0,0};
    f4 z20 = {0,0,0,0}, z21 = {0,0,0,0};
    #pragma unroll
    for (int kt = 0; kt < 4; ++kt) {
        int kc = kt * 32 + hi * 8;
        h8 a0 = *reinterpret_cast<const h8*>(&Ysh[swz(lo,      kc)]);
        h8 a1 = *reinterpret_cast<const h8*>(&Ysh[swz(16 + lo, kc)]);
        h8 a2 = *reinterpret_cast<const h8*>(&Ysh[swz(32 + lo, kc)]);
        h8 b0 = *reinterpret_cast<const h8*>(&W1T[(size_t)(w * 32 + lo) * DE + kc]);
        h8 b1 = *reinterpret_cast<const h8*>(&W1T[(size_t)(w * 32 + 16 + lo) * DE + kc]);
        z00 = __builtin_amdgcn_mfma_f32_16x16x32_f16(a0, b0, z00, 0, 0, 0);
        z01 = __builtin_amdgcn_mfma_f32_16x16x32_f16(a0, b1, z01, 0, 0, 0);
        z10 = __builtin_amdgcn_mfma_f32_16x16x32_f16(a1, b0, z10, 0, 0, 0);
        z11 = __builtin_amdgcn_mfma_f32_16x16x32_f16(a1, b1, z11, 0, 0, 0);
        z20 = __builtin_amdgcn_mfma_f32_16x16x32_f16(a2, b0, z20, 0, 0, 0);
        z21 = __builtin_amdgcn_mfma_f32_16x16x32_f16(a2, b1, z21, 0, 0, 0);
    }

    // e-contribution: p[mt][reg] = sum over this wave's 32 cols
    {
        float w2c0 = W2[w * 32 + lo];
        float w2c1 = W2[w * 32 + 16 + lo];
        float p0[4], p1[4], p2[4];
        #pragma unroll
        for (int reg = 0; reg < 4; ++reg) {
            p0[reg] = tanhf(z00[reg]) * w2c0 + tanhf(z01[reg]) * w2c1;
            p1[reg] = tanhf(z10[reg]) * w2c0 + tanhf(z11[reg]) * w2c1;
            p2[reg] = tanhf(z20[reg]) * w2c0 + tanhf(z21[reg]) * w2c1;
        }
        #pragma unroll
        for (int m = 1; m <= 8; m <<= 1) {
            #pragma unroll
            for (int reg = 0; reg < 4; ++reg) {
                p0[reg] += __shfl_xor(p0[reg], m);
                p1[reg] += __shfl_xor(p1[reg], m);
                p2[reg] += __shfl_xor(p2[reg], m);
            }
        }
        if (lo == 0) {
            #pragma unroll
            for (int reg = 0; reg < 4; ++reg) {
                int row = hi * 4 + reg;          // D-layout row within M-tile
                e_part[w][row]      = p0[reg];
                e_part[w][16 + row] = p1[reg];
                e_part[w][32 + row] = p2[reg];
            }
        }
    }
    __syncthreads();

    // ================= phase 3: softmax + OY (overwrites Ysh rows 0..15) ====
    {
        int ln = tid >> 4;
        int c0 = (tid & 15) * 8;
        float e0 = 0.f, e1 = 0.f, e2 = 0.f;
        #pragma unroll
        for (int ww = 0; ww < 4; ++ww) {
            e0 += e_part[ww][ln];
            e1 += e_part[ww][16 + ln];
            e2 += e_part[ww][32 + ln];
        }
        float mx = fmaxf(e0, fmaxf(e1, e2));
        float x0 = __expf(e0 - mx), x1 = __expf(e1 - mx), x2 = __expf(e2 - mx);
        float inv = 1.0f / (x0 + x1 + x2);
        float a0 = x0 * inv, a1 = x1 * inv, a2 = x2 * inv;

        h8 y0 = *reinterpret_cast<const h8*>(&Ysh[swz(ln,      c0)]);
        h8 y1 = *reinterpret_cast<const h8*>(&Ysh[swz(16 + ln, c0)]);
        h8 y2 = *reinterpret_cast<const h8*>(&Ysh[swz(32 + ln, c0)]);
        h8 o;
        #pragma unroll
        for (int j = 0; j < 8; ++j)
            o[j] = (_Float16)(a0 * (float)y0[j] + a1 * (float)y1[j] + a2 * (float)y2[j]);
        *reinterpret_cast<h8*>(&Ysh[swz(ln, c0)]) = o;
    }
    __syncthreads();

    // ================= phase 4: OUT = OY @ W3 (MFMA) =================
    {
        f4 o0 = {0,0,0,0}, o1 = {0,0,0,0};
        #pragma unroll
        for (int kt = 0; kt < 4; ++kt) {
            int kc = kt * 32 + hi * 8;
            h8 a  = *reinterpret_cast<const h8*>(&Ysh[swz(lo, kc)]);
            h8 b0 = *reinterpret_cast<const h8*>(&W3T[(size_t)(w * 32 + lo) * DE + kc]);
            h8 b1 = *reinterpret_cast<const h8*>(&W3T[(size_t)(w * 32 + 16 + lo) * DE + kc]);
            o0 = __builtin_amdgcn_mfma_f32_16x16x32_f16(a, b0, o0, 0, 0, 0);
            o1 = __builtin_amdgcn_mfma_f32_16x16x32_f16(a, b1, o1, 0, 0, 0);
        }
        int nodebase = blockIdx.x * NPB;
        #pragma unroll
        for (int reg = 0; reg < 4; ++reg) {
            int node = nodebase + hi * 4 + reg;
            if (node < N) {
                out[(size_t)node * DE + w * 32 + lo]      = o0[reg];
                out[(size_t)node * DE + w * 32 + 16 + lo] = o1[reg];
            }
        }
    }
}

// ---------------------------------------------------------------------------
// launch
// ---------------------------------------------------------------------------
extern "C" void kernel_launch(void* const* d_in, const int* in_sizes, int n_in,
                              void* d_out, int out_size, void* d_ws, size_t ws_size,
                              hipStream_t stream) {
    const float* E_C = (const float*)d_in[0];
    const float* E_D = (const float*)d_in[1];
    const float* E_M = (const float*)d_in[2];
    const int* dst_C = (const int*)d_in[3];
    const int* dst_D = (const int*)d_in[4];
    const int* dst_M = (const int*)d_in[5];
    const float* W1 = (const float*)d_in[7];
    const float* W2 = (const float*)d_in[8];
    const float* W3 = (const float*)d_in[9];
    float* out = (float*)d_out;

    const int N = out_size / DE;                     // 100000
    const int nE[3] = { in_sizes[3], in_sizes[4], in_sizes[5] };
    const int nEmax = max(nE[0], max(nE[1], nE[2]));

    // ws: eid[3*N*CAP] ints | cnt[3N] ints | W1T[16384] f16 | W3T[16384] f16
    int* eid = (int*)d_ws;
    int* cnt = eid + (size_t)3 * N * CAP;
    __half* W1T = (__half*)(cnt + (size_t)3 * N);
    __half* W3T = W1T + DE * DE;

    (void)hipMemsetAsync(cnt, 0, 3 * (size_t)N * sizeof(int), stream);
    prep_w<<<(DE * DE + 255) / 256, 256, 0, stream>>>(W1, W3, W1T, W3T);

    {
        dim3 grid((nEmax + 1023) / 1024, 3);
        fill_direct4<<<grid, 256, 0, stream>>>(dst_C, dst_D, dst_M, cnt, eid,
                                               N, nE[0], nE[1], nE[2]);
    }

    int nblocks = (N + NPB - 1) / NPB;
    node_fused<<<nblocks, 256, 0, stream>>>(
        E_C, E_D, E_M, eid, cnt, W1T, W2, W3T, out, N);
}